// Round 5
// baseline (2218.018 us; speedup 1.0000x reference)
//
#include <hip/hip_runtime.h>

#define B_ 64
#define T_ 512
#define E_ 512
#define H_ 1024
#define C_ 20
#define NBLK 256
#define RING 16
#define BH (B_ * H_)

typedef __attribute__((ext_vector_type(8))) __bf16 bf16x8;
typedef __attribute__((ext_vector_type(4))) float f32x4;
typedef unsigned long long u64;

__device__ __forceinline__ short f2bf(float x){
  unsigned u = __float_as_uint(x);
  unsigned r = (u + 0x7fffu + ((u >> 16) & 1u)) >> 16;   // RNE
  return (short)r;
}
__device__ __forceinline__ float bf2f(short s){
  return __uint_as_float(((unsigned)(unsigned short)s) << 16);
}

// Relaxed agent-scope ops: single coherent-point (IC) instructions; no
// buffer_inv / buffer_wbl2 anywhere in the persistent loop.
__device__ __forceinline__ u64 ld_agent_u64(const u64* p){
  return __hip_atomic_load(p, __ATOMIC_RELAXED, __HIP_MEMORY_SCOPE_AGENT);
}
__device__ __forceinline__ void st_agent_u64(u64* p, u64 v){
  __hip_atomic_store(p, v, __ATOMIC_RELAXED, __HIP_MEMORY_SCOPE_AGENT);
}

// ---------------------------------------------------------------------------
// Prep: W -> hi/lo bf16 splits, x -> bf16, init h-ring (slot0 = h0 = zeros,
// slots 1..15 = 0xFFFF sentinel). Ring MUST be re-inited every launch (ws is
// not re-poisoned between graph replays).
// ---------------------------------------------------------------------------
__global__ void prep_kernel(const float* __restrict__ x,
                            const float* __restrict__ wih,
                            const float* __restrict__ whh,
                            short* __restrict__ whhh, short* __restrict__ whhl,
                            short* __restrict__ wihh, short* __restrict__ wihl,
                            short* __restrict__ hring,
                            short* __restrict__ xb)
{
  const long NH = (long)H_ * H_;
  const long NI = (long)H_ * E_;
  const long NR = (long)RING * BH;
  const long NX = xb ? (long)B_ * T_ * E_ : 0;
  const long TOT = NH + NI + NR + NX;
  long i = (long)blockIdx.x * blockDim.x + threadIdx.x;
  const long stride = (long)gridDim.x * blockDim.x;
  for (; i < TOT; i += stride){
    if (i < NH){
      float v = whh[i]; short hi = f2bf(v);
      whhh[i] = hi; whhl[i] = f2bf(v - bf2f(hi));
    } else if (i < NH + NI){
      long j = i - NH; float v = wih[j]; short hi = f2bf(v);
      wihh[j] = hi; wihl[j] = f2bf(v - bf2f(hi));
    } else if (i < NH + NI + NR){
      long j = i - NH - NI;
      hring[j] = (j < BH) ? (short)0 : (short)0xFFFF;   // h0 zeros, rest sentinel
    } else {
      long j = i - NH - NI - NR;
      xb[j] = f2bf(x[j]);
    }
  }
}

// ---------------------------------------------------------------------------
// Persistent scan. 256 blocks; bg = (blk&7)>>1 (XCD-pair aligned under the %8
// round-robin heuristic — perf only, correctness mapping-independent),
// cg = ((blk>>3)<<1)|(blk&1). Block tile C[16x16], K split over 4 waves.
// Weights pinned in regs (hi+lo bf16).
//
// Per-step serial-latency diet:
//  - sentinel-validated data polling (detect == fetch), ring of 16 slots,
//    early re-sentinel of slot t+8 (safety window 7 steps; poll-loop vmcnt
//    drains make the commit-order guarantee — no explicit store-ack wait).
//  - x pipeline: issue x(t+2) loads early in step t (before the publish store
//    so no store-ack drain at the register rotate), compute xq(t+1) from
//    registers loaded a full step earlier — no HBM stall in the chain.
//  - raw lgkmcnt-only barrier (no vmcnt drain) for the LDS reduce.
//  - reduce/tanh/publish spread across all 4 waves (lanes 0-15 each).
// ---------------------------------------------------------------------------
__global__ __launch_bounds__(256, 2) void rnn_scan(
    const float* __restrict__ x, const short* __restrict__ xb,
    const short* __restrict__ wihh, const short* __restrict__ wihl,
    const short* __restrict__ whhh, const short* __restrict__ whhl,
    const float* __restrict__ bih, const float* __restrict__ bhh,
    short* __restrict__ hring, float* __restrict__ hT)
{
  const int tid  = threadIdx.x;
  const int lane = tid & 63;
  const int wv   = tid >> 6;                    // wave 0..3 -> K quarter
  const int bg   = (blockIdx.x & 7) >> 1;       // batch group 0..3 (XCD pair)
  const int cg   = ((blockIdx.x >> 3) << 1) | (blockIdx.x & 1);  // col group
  const int r16  = lane & 15;
  const int kq   = lane >> 4;                   // 0..3

  __shared__ float redbuf[2][1024];

  const int colRow = cg * 16 + r16;   // output col == W row
  const int hrow   = bg * 16 + r16;   // batch row

  // --- weight fragments, loaded once then pinned ---
  bf16x8 whhHi[8], whhLo[8];
  #pragma unroll
  for (int c = 0; c < 8; c++){
    int k0 = wv * 256 + c * 32 + kq * 8;
    whhHi[c] = *(const bf16x8*)(whhh + (long)colRow * H_ + k0);
    whhLo[c] = *(const bf16x8*)(whhl + (long)colRow * H_ + k0);
  }
  bf16x8 wihHi[4], wihLo[4];
  #pragma unroll
  for (int c = 0; c < 4; c++){
    int k0 = wv * 128 + c * 32 + kq * 8;
    wihHi[c] = *(const bf16x8*)(wihh + (long)colRow * E_ + k0);
    wihLo[c] = *(const bf16x8*)(wihl + (long)colRow * E_ + k0);
  }
  float bias = bih[colRow] + bhh[colRow];
  #pragma unroll
  for (int c = 0; c < 8; c++)
    asm volatile("" : "+v"(whhHi[c]), "+v"(whhLo[c]));
  #pragma unroll
  for (int c = 0; c < 4; c++)
    asm volatile("" : "+v"(wihHi[c]), "+v"(wihLo[c]));
  asm volatile("" : "+v"(bias));

  // consumer fragment offset
  const int haOff = hrow * H_ + wv * 256 + kq * 8;
  // producer / reducer mapping: lanes 0-15 of EACH wave own 4 outputs
  const int prow   = wv * 4 + (lane >> 2);      // 0..15 (row of 16x16 tile)
  const int pcol   = (lane & 3) * 4;            // col0 of 8B granule
  const int pubOff = (bg * 16 + prow) * H_ + cg * 16 + pcol;

  auto load_xa = [&](int tn, int c) -> bf16x8 {
    int k0 = wv * 128 + c * 32 + kq * 8;
    if (xb){
      return *(const bf16x8*)(xb + ((long)hrow * T_ + tn) * E_ + k0);
    } else {
      const float* xp = x + ((long)hrow * T_ + tn) * E_ + k0;
      float4 f0 = *(const float4*)xp;
      float4 f1 = *(const float4*)(xp + 4);
      union { short s[8]; bf16x8 v; } u;
      u.s[0]=f2bf(f0.x); u.s[1]=f2bf(f0.y); u.s[2]=f2bf(f0.z); u.s[3]=f2bf(f0.w);
      u.s[4]=f2bf(f1.x); u.s[5]=f2bf(f1.y); u.s[6]=f2bf(f1.z); u.s[7]=f2bf(f1.w);
      return u.v;
    }
  };

  // prologue: xq(0) computed directly; x(1) staged into regs; x(2) issued in
  // the first loop iteration.
  f32x4 xq;
  {
    float b0 = (wv == 0) ? bias : 0.f;
    f32x4 aH = { b0, b0, b0, b0 };
    f32x4 aL = { 0.f, 0.f, 0.f, 0.f };
    #pragma unroll
    for (int c = 0; c < 4; c++){
      bf16x8 xa = load_xa(0, c);
      aH = __builtin_amdgcn_mfma_f32_16x16x32_bf16(xa, wihHi[c], aH, 0, 0, 0);
      aL = __builtin_amdgcn_mfma_f32_16x16x32_bf16(xa, wihLo[c], aL, 0, 0, 0);
    }
    xq = aH + aL;
  }
  bf16x8 xa_cur[4], xa_nxt[4];
  #pragma unroll
  for (int c = 0; c < 4; c++) xa_cur[c] = load_xa(1, c);

  for (int t = 0; t < T_; ++t){
    const short* hb = hring + (long)(t & (RING - 1)) * BH + haOff;

    // ---- poll + load h fragments (sentinel-validated, detect==fetch) ----
    bf16x8 ha[8];
    unsigned need = 0xFFu;
    do {
      u64 q0[8], q1[8];
      #pragma unroll
      for (int c = 0; c < 8; c++){
        if (need & (1u << c)){
          q0[c] = ld_agent_u64((const u64*)(hb + c * 32));
          q1[c] = ld_agent_u64((const u64*)(hb + c * 32) + 1);
        }
      }
      #pragma unroll
      for (int c = 0; c < 8; c++){
        if (need & (1u << c)){
          bool bad = (((unsigned)q0[c] & 0xFFFFu) == 0xFFFFu) ||
                     (((unsigned)q1[c] & 0xFFFFu) == 0xFFFFu);
          if (!__any(bad)){
            union { u64 q[2]; bf16x8 v; } u;
            u.q[0] = q0[c]; u.q[1] = q1[c];
            ha[c] = u.v;
            need &= ~(1u << c);
          }
        }
      }
    } while (need);

    // ---- early re-sentinel of slot (t+8): holds h[t-8], reads provably done ----
    if (lane < 16 && t + 8 < T_)
      st_agent_u64((u64*)(hring + (long)((t + 8) & (RING - 1)) * BH + pubOff),
                   0xFFFFFFFFFFFFFFFFull);

    // ---- issue x(t+2) loads NOW (fire-and-forget; consumed next step) ----
    if (t + 2 < T_){
      #pragma unroll
      for (int c = 0; c < 4; c++) xa_nxt[c] = load_xa(t + 2, c);
    }

    // ---- recurrent GEMM, two independent accumulator chains (hi / lo) ----
    f32x4 accH = xq;
    f32x4 accL = { 0.f, 0.f, 0.f, 0.f };
    #pragma unroll
    for (int c = 0; c < 8; c++){
      accH = __builtin_amdgcn_mfma_f32_16x16x32_bf16(ha[c], whhHi[c], accH, 0, 0, 0);
      accL = __builtin_amdgcn_mfma_f32_16x16x32_bf16(ha[c], whhLo[c], accL, 0, 0, 0);
    }
    f32x4 acc = accH + accL;

    // ---- K-partials to LDS (double-buffered), lgkm-only barrier ----
    float* rb = redbuf[t & 1];
    #pragma unroll
    for (int i = 0; i < 4; i++)
      rb[wv * 256 + (kq * 4 + i) * 16 + r16] = acc[i];
    asm volatile("s_waitcnt lgkmcnt(0)\n\ts_barrier" ::: "memory");

    // ---- spread reduce + tanh + publish (lanes 0-15 of every wave) ----
    if (lane < 16){
      const int e = prow * 16 + pcol;
      f32x4 s = *(const f32x4*)&rb[e];
      s += *(const f32x4*)&rb[256 + e];
      s += *(const f32x4*)&rb[512 + e];
      s += *(const f32x4*)&rb[768 + e];
      float hv[4];
      #pragma unroll
      for (int j = 0; j < 4; j++){
        float a  = fabsf(s[j]);
        float ex = __expf(-2.f * a);
        float r  = (1.f - ex) / (1.f + ex);
        hv[j] = copysignf(r, s[j]);
      }
      if (t < T_ - 1){
        u64 pk =  (u64)(unsigned short)f2bf(hv[0])
               | ((u64)(unsigned short)f2bf(hv[1]) << 16)
               | ((u64)(unsigned short)f2bf(hv[2]) << 32)
               | ((u64)(unsigned short)f2bf(hv[3]) << 48);
        st_agent_u64((u64*)(hring + (long)((t + 1) & (RING - 1)) * BH + pubOff), pk);
      } else {
        *(float4*)(hT + pubOff) = make_float4(hv[0], hv[1], hv[2], hv[3]);
      }
    }
    if (t == T_ - 1) break;

    // ---- xq for t+1 from registers staged a full step ago (no HBM stall) ----
    {
      float b0 = (wv == 0) ? bias : 0.f;
      f32x4 aH = { b0, b0, b0, b0 };
      f32x4 aL = { 0.f, 0.f, 0.f, 0.f };
      #pragma unroll
      for (int c = 0; c < 4; c++){
        aH = __builtin_amdgcn_mfma_f32_16x16x32_bf16(xa_cur[c], wihHi[c], aH, 0, 0, 0);
        aL = __builtin_amdgcn_mfma_f32_16x16x32_bf16(xa_cur[c], wihLo[c], aL, 0, 0, 0);
      }
      xq = aH + aL;
    }
    // rotate the x pipeline (vmcnt wait here tolerates the in-flight publish
    // store: loads are older than the store, so no store-ack stall)
    #pragma unroll
    for (int c = 0; c < 4; c++) xa_cur[c] = xa_nxt[c];
  }
}

// ---------------------------------------------------------------------------
// Head: y1 = relu(hT @ fc1_w^T + b1);  out = y1 @ fc2_w^T + b2   (all fp32)
// ---------------------------------------------------------------------------
__global__ void fc1_kernel(const float* __restrict__ hT, const float* __restrict__ w1,
                           const float* __restrict__ b1, float* __restrict__ y1)
{
  int o = blockIdx.x * 256 + threadIdx.x;     // 0..65535
  int b = o >> 10, j = o & 1023;
  const float4* hp = (const float4*)(hT + (long)b * H_);
  const float4* wp = (const float4*)(w1 + (long)j * H_);
  float s = 0.f;
  #pragma unroll 4
  for (int k = 0; k < H_ / 4; k++){
    float4 hv = hp[k], wv = wp[k];
    s += hv.x * wv.x + hv.y * wv.y + hv.z * wv.z + hv.w * wv.w;
  }
  s += b1[j];
  y1[o] = s > 0.f ? s : 0.f;
}

__global__ void fc2_kernel(const float* __restrict__ y1, const float* __restrict__ w2,
                           const float* __restrict__ b2, float* __restrict__ out)
{
  __shared__ float ybuf[H_];
  int b = blockIdx.x;
  for (int k = threadIdx.x; k < H_; k += 256) ybuf[k] = y1[(long)b * H_ + k];
  __syncthreads();
  if (threadIdx.x < C_){
    const float* wp = w2 + (long)threadIdx.x * H_;
    float s = 0.f;
    for (int k = 0; k < H_; k++) s += ybuf[k] * wp[k];
    out[b * C_ + threadIdx.x] = s + b2[threadIdx.x];
  }
}

// ---------------------------------------------------------------------------
extern "C" void kernel_launch(void* const* d_in, const int* in_sizes, int n_in,
                              void* d_out, int out_size, void* d_ws, size_t ws_size,
                              hipStream_t stream)
{
  const float* x   = (const float*)d_in[0];
  const float* wih = (const float*)d_in[1];
  const float* whh = (const float*)d_in[2];
  const float* bih = (const float*)d_in[3];
  const float* bhh = (const float*)d_in[4];
  const float* w1  = (const float*)d_in[5];
  const float* b1  = (const float*)d_in[6];
  const float* w2  = (const float*)d_in[7];
  const float* b2  = (const float*)d_in[8];
  float* out = (float*)d_out;

  char* ws = (char*)d_ws;
  size_t off = 0;
  auto carve = [&](size_t bytes) -> char* {
    char* p = ws + off; off += (bytes + 255) & ~(size_t)255; return p;
  };
  short*  whhh  = (short*)carve((size_t)H_ * H_ * 2);
  short*  whhl  = (short*)carve((size_t)H_ * H_ * 2);
  short*  wihh  = (short*)carve((size_t)H_ * E_ * 2);
  short*  wihl  = (short*)carve((size_t)H_ * E_ * 2);
  short*  hring = (short*)carve((size_t)RING * BH * 2);
  float*  hT    = (float*)carve((size_t)B_ * H_ * 4);
  float*  y1    = (float*)carve((size_t)B_ * H_ * 4);
  size_t xbytes = (size_t)B_ * T_ * E_ * 2;
  short* xb = (off + xbytes <= ws_size) ? (short*)carve(xbytes) : nullptr;

  prep_kernel<<<2048, 256, 0, stream>>>(x, wih, whh, whhh, whhl, wihh, wihl,
                                        hring, xb);
  rnn_scan<<<NBLK, 256, 0, stream>>>(x, xb, wihh, wihl, whhh, whhl,
                                     bih, bhh, hring, hT);
  fc1_kernel<<<256, 256, 0, stream>>>(hT, w1, b1, y1);
  fc2_kernel<<<64, 256, 0, stream>>>(y1, w2, b2, out);
}